// Round 10
// baseline (173.985 us; speedup 1.0000x reference)
//
#include <hip/hip_runtime.h>
#include <hip/hip_bf16.h>
#include <hip/hip_cooperative_groups.h>

// EfficientAttention: x(4,256,64,64) -> qkv(192ch) -> attn(N=4096,c=64) -> proj(256ch)
// ONE cooperative kernel (grid 256 x 512): qkv phase -> grid.sync -> attn phase.
// Clock insight (r9): chip runs ~600 MHz on this bench; kernels are VALU-issue
// bound at real clock -> minimize instructions + launches.
//   Qf/Kf ws: [b][chunk32][kk(4)][lane(64)][8]
//   Vf   ws: [b][chunk32][ct(2)ks(2)][lane(64)][j(8)] = producer reg order
// attn: LDS-DMA dbuf (256-token tiles, 16 barriers); S regs ARE the O-MFMA
// A-operand; den via MFMA against ones-frag (no VALU adds, no shfl).

#define N_TOK 4096
#define CDIM  64
#define DIM   256
#define NBAT  4

typedef __attribute__((ext_vector_type(8)))  short          short8;
typedef __attribute__((ext_vector_type(8)))  unsigned short ushort8_t;
typedef __attribute__((ext_vector_type(4)))  unsigned short ushort4_t;
typedef __attribute__((ext_vector_type(2)))  unsigned int   uint2_t;
typedef __attribute__((ext_vector_type(4)))  unsigned int   uint4_t;
typedef __attribute__((ext_vector_type(4)))  float          float4_t;
typedef __attribute__((ext_vector_type(16))) float          float16_t;

#define QSC  0.18033688011112042f   /* 0.125 * log2(e): p = exp2(s) */
#define PEXP(x) __builtin_amdgcn_exp2f(x)

// packed f32x2 -> bf16x2 dword (v_cvt_pk_bf16_f32, RNE)
__device__ __forceinline__ unsigned int pkcv(float a, float b) {
  __hip_bfloat162 h = __float22bfloat162_rn(make_float2(a, b));
  unsigned int r; __builtin_memcpy(&r, &h, 4); return r;
}

__device__ __forceinline__ short8 ld8(const unsigned short* p) {
  return __builtin_bit_cast(short8, *(const ushort8_t*)p);
}

__device__ __forceinline__ short8 pack8f(float4_t a, float4_t b) {
  uint4_t u;
  u[0] = pkcv(a[0], a[1]); u[1] = pkcv(a[2], a[3]);
  u[2] = pkcv(b[0], b[1]); u[3] = pkcv(b[2], b[3]);
  return __builtin_bit_cast(short8, u);
}

__device__ __forceinline__ float16_t z16() {
  float16_t r;
#pragma unroll
  for (int i = 0; i < 16; ++i) r[i] = 0.0f;
  return r;
}

// async global->LDS DMA: 64 lanes x 16B; LDS dst = wave-uniform base
typedef __attribute__((address_space(1))) const void* gvp;
typedef __attribute__((address_space(3))) void*       lvp;
__device__ __forceinline__ void dma16(const unsigned short* g, unsigned short* l) {
  __builtin_amdgcn_global_load_lds((gvp)g, (lvp)l, 16, 0, 0);
}

#define MFMA(a, b, c) __builtin_amdgcn_mfma_f32_32x32x16_bf16((a), (b), (c), 0, 0, 0)

// ws layout (u16 units)
#define QOFF  0                // 4*128*4*512 = 1048576 each
#define KOFF  1048576
#define VOFF  2097152

#define RS   132   // Xl row stride (dwords), phase A
#define OS   68    // Oacc row stride (fp32)
#define OLS  72    // Ol row stride (bf16)
#define NACC (64 * OS + 64)

// shared memory: phase A Xl (33.8KB) aliases phase B KV (128KB)
#define SM_BYTES (131072 + NACC * 4 + 64 * OLS * 2)

__global__ __launch_bounds__(512, 2) void k_fused(
    const float* __restrict__ x, const float* __restrict__ qw,
    const float* __restrict__ qb, unsigned short* __restrict__ Qf,
    unsigned short* __restrict__ Kf, unsigned short* __restrict__ Vf,
    const float* __restrict__ pw, const float* __restrict__ pb,
    float* __restrict__ out)
{
  __shared__ __align__(16) unsigned char SM[SM_BYTES];
  unsigned short* KVb = (unsigned short*)SM;                 // [buf][K|V][16384]
  float*          Oacc = (float*)(SM + 131072);
  unsigned short* Ol   = (unsigned short*)(SM + 131072 + NACC * 4);
  unsigned int*   Xl   = (unsigned int*)SM;                  // phase A alias

  const int id = blockIdx.x;
  const int b  = (id >> 1) & 3;                              // batch -> XCD pair
  const int nt = (id & 1) | ((id >> 3) << 1);                // 0..63 (64-token tile)
  const int t  = threadIdx.x;
  const int wv = t >> 6, lane = t & 63, l31 = lane & 31, lh = lane >> 5;

  // ======================== PHASE A: qkv ========================
  {
    const int n0g = nt * 64;

    // per-wave weight frags (waves 0-5), fp32 -> bf16 regs; QSC folded for Q
    short8 wf[16];
    if (wv < 6) {
      const float sc = (wv < 2) ? QSC : 1.0f;
      const float* wbase = qw + (wv * 32 + l31) * 256 + lh * 8;
#pragma unroll
      for (int kk = 0; kk < 16; ++kk) {
        float4_t a = *(const float4_t*)(wbase + kk * 16);
        float4_t c = *(const float4_t*)(wbase + kk * 16 + 4);
#pragma unroll
        for (int j = 0; j < 4; ++j) { a[j] *= sc; c[j] *= sc; }
        wf[kk] = pack8f(a, c);
      }
    }

    // stage x tile (256c x 64n) transposed -> Xl[n][cpair], all 512 threads
    {
      const int n0  = (t & 15) * 4;
      const int cpb = t >> 4;                      // 0..31
#pragma unroll
      for (int p = 0; p < 4; ++p) {
        const int cp = cpb + 32 * p, c = cp * 2;
        const float* xb = x + (((size_t)(b * DIM + c)) << 12) + n0g + n0;
        float4_t a = *(const float4_t*)xb;
        float4_t d = *(const float4_t*)(xb + 4096);
#pragma unroll
        for (int j = 0; j < 4; ++j)
          Xl[(n0 + j) * RS + cp] = pkcv(a[j], d[j]);
      }
    }
    __syncthreads();

    if (wv < 6) {
      const unsigned int* xr0 = &Xl[l31 * RS + lh * 4];
      const unsigned int* xr1 = &Xl[(32 + l31) * RS + lh * 4];
      float16_t a0 = z16(), a1 = z16();
      if (wv < 4) {
#pragma unroll
        for (int kk = 0; kk < 16; ++kk) {
          short8 x0 = __builtin_bit_cast(short8, *(const uint4_t*)(xr0 + kk * 8));
          short8 x1 = __builtin_bit_cast(short8, *(const uint4_t*)(xr1 + kk * 8));
          a0 = MFMA(wf[kk], x0, a0);               // C[o rows][n cols]
          a1 = MFMA(wf[kk], x1, a1);
        }
      } else {
#pragma unroll
        for (int kk = 0; kk < 16; ++kk) {
          short8 x0 = __builtin_bit_cast(short8, *(const uint4_t*)(xr0 + kk * 8));
          short8 x1 = __builtin_bit_cast(short8, *(const uint4_t*)(xr1 + kk * 8));
          a0 = MFMA(x0, wf[kk], a0);               // C[token rows][c cols]
          a1 = MFMA(x1, wf[kk], a1);
        }
      }

      if (wv < 4) {
        unsigned short* dst = (wv < 2) ? Qf : Kf;
        const int w2 = wv & 1;                     // c64-half of Q or K
        const float bsc = (wv < 2) ? QSC : 1.0f;
#pragma unroll
        for (int sub = 0; sub < 2; ++sub) {
          const float16_t& aa = sub ? a1 : a0;
          const int ch = nt * 2 + sub;
#pragma unroll
          for (int p = 0; p < 4; ++p) {
            const int o = wv * 32 + p * 8 + lh * 4;
            float4_t bv = *(const float4_t*)(qb + o);
            uint2_t u2;
            u2[0] = pkcv(aa[p * 4 + 0] + bv[0] * bsc, aa[p * 4 + 1] + bv[1] * bsc);
            u2[1] = pkcv(aa[p * 4 + 2] + bv[2] * bsc, aa[p * 4 + 3] + bv[3] * bsc);
            const int kkt = w2 * 2 + (p >> 1);
            *(uint2_t*)(dst + ((((b * 128 + ch) * 4 + kkt) << 9)
                               + (l31 + 32 * (p & 1)) * 8 + lh * 4)) = u2;
          }
        }
      } else {
        const int ct = wv - 4;
        const float bvs = qb[128 + ct * 32 + l31];
#pragma unroll
        for (int sub = 0; sub < 2; ++sub) {
          const float16_t& aa = sub ? a1 : a0;
          const int ch = nt * 2 + sub;
#pragma unroll
          for (int ks = 0; ks < 2; ++ks) {
            uint4_t u4;
#pragma unroll
            for (int j = 0; j < 4; ++j)
              u4[j] = pkcv(aa[ks * 8 + 2 * j] + bvs, aa[ks * 8 + 2 * j + 1] + bvs);
            *(uint4_t*)(Vf + ((((b * 128 + ch) * 4 + ct * 2 + ks) << 9)
                              + lane * 8)) = u4;
          }
        }
      }
    }
  }

  cooperative_groups::this_grid().sync();

  // ======================== PHASE B: attn + proj ========================
  const int mq = wv >> 1, nsub = wv & 1;

  for (int i = t; i < NACC; i += 512) Oacc[i] = 0.0f;

  // staging role: wave stages 2 chunks of K (wv<4) or V (wv>=4); 8KB/tile
  const int kvsel = wv >> 2;
  const int wq2   = (wv & 3) * 2;
  const unsigned short* sg = ((kvsel == 0) ? Kf : Vf)
                             + (((size_t)(b * 128 + wq2)) << 11) + lane * 8;
  unsigned short* KVbase = KVb + kvsel * 16384;

  // Q frags (QSC pre-folded)
  short8 qf[4];
#pragma unroll
  for (int kk = 0; kk < 4; ++kk)
    qf[kk] = ld8(Qf + (((b * 128 + nt * 2 + nsub) * 4 + kk) << 9) + lane * 8);

  // ones B-frag for den-MFMA
  uint4_t one4; one4[0] = 0x3F803F80u; one4[1] = 0x3F803F80u;
  one4[2] = 0x3F803F80u; one4[3] = 0x3F803F80u;
  const short8 ONES = __builtin_bit_cast(short8, one4);

  // stage tile 0 into buf 0
#pragma unroll
  for (int c2 = 0; c2 < 2; ++c2)
#pragma unroll
    for (int kk = 0; kk < 4; ++kk)
      dma16(sg + (c2 << 11) + (kk << 9),
            KVbase + ((wq2 + c2) << 11) + (kk << 9));

  float16_t oc0 = z16(), oc1 = z16(), dacc = z16();

  __syncthreads();   // Oacc zeroed + tile 0 resident

  for (int t4 = 0; t4 < 16; ++t4) {
    const int cur = t4 & 1;

    if (t4 < 15) {   // stage tile t4+1, drained a full tile later
      const unsigned short* g = sg + (((size_t)(t4 + 1)) << 14);
      unsigned short* ldst = KVbase + (cur ^ 1) * 32768;
#pragma unroll
      for (int c2 = 0; c2 < 2; ++c2)
#pragma unroll
        for (int kk = 0; kk < 4; ++kk)
          dma16(g + (c2 << 11) + (kk << 9),
                ldst + ((wq2 + c2) << 11) + (kk << 9));
    }

#pragma unroll
    for (int cc = 0; cc < 2; ++cc) {
      const int ch = mq * 2 + cc;
      const unsigned short* kl = KVb + cur * 32768 + (ch << 11);
      const unsigned short* vl = KVb + cur * 32768 + 16384 + (ch << 11);

      short8 kf0 = ld8(kl + lane * 8);
      short8 kf1 = ld8(kl + 512 + lane * 8);
      short8 kf2 = ld8(kl + 1024 + lane * 8);
      short8 kf3 = ld8(kl + 1536 + lane * 8);

      float16_t s = z16();
      s = MFMA(kf0, qf[0], s);
      s = MFMA(kf1, qf[1], s);
      s = MFMA(kf2, qf[2], s);
      s = MFMA(kf3, qf[3], s);

      float p[16];
#pragma unroll
      for (int e = 0; e < 16; ++e) p[e] = PEXP(s[e]);

      // S regs ARE the O-MFMA A-operand (V k-slots pre-permuted at production)
      uint4_t w0, w1;
#pragma unroll
      for (int j = 0; j < 4; ++j) {
        w0[j] = pkcv(p[2 * j], p[2 * j + 1]);
        w1[j] = pkcv(p[8 + 2 * j], p[9 + 2 * j]);
      }
      short8 pf0 = __builtin_bit_cast(short8, w0);   // m 0..15 of chunk
      short8 pf1 = __builtin_bit_cast(short8, w1);   // m 16..31

      short8 vf0 = ld8(vl + lane * 8);
      short8 vf1 = ld8(vl + 512 + lane * 8);
      short8 vf2 = ld8(vl + 1024 + lane * 8);
      short8 vf3 = ld8(vl + 1536 + lane * 8);

      oc0  = MFMA(pf0, vf0, oc0);
      oc0  = MFMA(pf1, vf1, oc0);
      oc1  = MFMA(pf0, vf2, oc1);
      oc1  = MFMA(pf1, vf3, oc1);
      dacc = MFMA(pf0, ONES, dacc);   // den[n] in every col
      dacc = MFMA(pf1, ONES, dacc);
    }

    __syncthreads();   // drains next-tile DMA + frees cur buffer
  }

  // combine m-chunk partials: O[n][c] + den via LDS atomics
#pragma unroll
  for (int ct = 0; ct < 2; ++ct) {
    const float16_t& oa = ct ? oc1 : oc0;
    const int cc = ct * 32 + l31;
#pragma unroll
    for (int e = 0; e < 16; ++e) {
      const int nr = nsub * 32 + (e & 3) + 8 * (e >> 2) + 4 * lh;
      atomicAdd(&Oacc[nr * OS + cc], oa[e]);
    }
  }
  if (l31 == 0) {   // dacc cols identical; 2 lanes (lh 0/1) cover 32 rows
#pragma unroll
    for (int e = 0; e < 16; ++e) {
      const int nr = nsub * 32 + (e & 3) + 8 * (e >> 2) + 4 * lh;
      atomicAdd(&Oacc[64 * OS + nr], dacc[e]);
    }
  }
  __syncthreads();

  // normalize + cast -> Ol[n][c] bf16 (8 thr/row)
  {
    const int nloc = t >> 3, c8 = (t & 7) * 8;
    float4_t s0 = *(float4_t*)&Oacc[nloc * OS + c8];
    float4_t s1 = *(float4_t*)&Oacc[nloc * OS + c8 + 4];
    const float r = 1.0f / Oacc[64 * OS + nloc];
    uint4_t o4;
    o4[0] = pkcv(s0[0] * r, s0[1] * r);
    o4[1] = pkcv(s0[2] * r, s0[3] * r);
    o4[2] = pkcv(s1[0] * r, s1[1] * r);
    o4[3] = pkcv(s1[2] * r, s1[3] * r);
    *(uint4_t*)&Ol[nloc * OLS + c8] = o4;
  }
  __syncthreads();

  // fused proj: wave wv -> o-tile wv (32 o), both n-subtiles; raw fp32 W
  float16_t f0 = z16(), f1 = z16();
  const float* pwrow = pw + (wv * 32 + l31) * 64 + lh * 8;
#pragma unroll
  for (int kk = 0; kk < 4; ++kk) {
    float4_t wa = *(const float4_t*)(pwrow + kk * 16);
    float4_t wb = *(const float4_t*)(pwrow + kk * 16 + 4);
    short8 af = pack8f(wa, wb);
    short8 b0 = ld8(&Ol[l31 * OLS + kk * 16 + lh * 8]);
    short8 b1 = ld8(&Ol[(32 + l31) * OLS + kk * 16 + lh * 8]);
    f0 = MFMA(af, b0, f0);
    f1 = MFMA(af, b1, f1);
  }
  const int n0 = nt * 64;
#pragma unroll
  for (int e = 0; e < 16; ++e) {
    const int o = wv * 32 + (e & 3) + 8 * (e >> 2) + 4 * lh;
    const float bv = pb[o];
    out[((b * 256 + o) << 12) + n0 + l31]      = f0[e] + bv;
    out[((b * 256 + o) << 12) + n0 + 32 + l31] = f1[e] + bv;
  }
}

extern "C" void kernel_launch(void* const* d_in, const int* in_sizes, int n_in,
                              void* d_out, int out_size, void* d_ws, size_t ws_size,
                              hipStream_t stream) {
  const float* x      = (const float*)d_in[0];
  const float* qkv_w  = (const float*)d_in[1];
  const float* qkv_b  = (const float*)d_in[2];
  const float* proj_w = (const float*)d_in[3];
  const float* proj_b = (const float*)d_in[4];
  float* outp = (float*)d_out;

  unsigned short* ws = (unsigned short*)d_ws;
  unsigned short* qf = ws + QOFF;
  unsigned short* kf = ws + KOFF;
  unsigned short* vf = ws + VOFF;

  void* args[] = { (void*)&x, (void*)&qkv_w, (void*)&qkv_b,
                   (void*)&qf, (void*)&kf, (void*)&vf,
                   (void*)&proj_w, (void*)&proj_b, (void*)&outp };
  hipLaunchCooperativeKernel((const void*)k_fused, dim3(256), dim3(512),
                             args, 0, stream);
}

// Round 11
// 132.776 us; speedup vs baseline: 1.3104x; 1.3104x over previous
//
#include <hip/hip_runtime.h>
#include <hip/hip_bf16.h>

// EfficientAttention: x(4,256,64,64) -> qkv(192ch) -> attn(N=4096,c=64) -> proj(256ch)
// 3 regular launches (cooperative launch costs +40us in this harness - r10).
// k_prep: qkv weights fp32->bf16 frag layout (QSC folded into Q rows/bias).
// k_qkv : 256 blocks x 64-token tiles; Xl XOR-granule-swizzled (8-way -> 2-way
//         write conflicts, reads stay perfect). Frag-swizzled outputs:
//   Qf/Kf: [b][chunk32][kk(4)][lane(64)][8]
//   Vf   : [b][chunk32][ct(2)ks(2)][lane(64)][j(8)] = producer reg order
// k_attn: 256-token K/V LDS-DMA dbuf tiles (16 barriers); S regs ARE the
//         O-MFMA A-operand; den via MFMA-with-ones (no VALU adds / shfl).
// Block->batch: b = id&3 so each XCD serves one batch (K/V fit 4MB L2).

#define N_TOK 4096
#define CDIM  64
#define DIM   256
#define NBAT  4

typedef __attribute__((ext_vector_type(8)))  short          short8;
typedef __attribute__((ext_vector_type(8)))  unsigned short ushort8_t;
typedef __attribute__((ext_vector_type(4)))  unsigned short ushort4_t;
typedef __attribute__((ext_vector_type(2)))  unsigned int   uint2_t;
typedef __attribute__((ext_vector_type(4)))  unsigned int   uint4_t;
typedef __attribute__((ext_vector_type(4)))  float          float4_t;
typedef __attribute__((ext_vector_type(16))) float          float16_t;

#define QSC  0.18033688011112042f   /* 0.125 * log2(e): p = exp2(s) */
#define PEXP(x) __builtin_amdgcn_exp2f(x)

__device__ __forceinline__ unsigned short f2bf(float f) {
  unsigned int u = __builtin_bit_cast(unsigned int, f);
  u += 0x7fffu + ((u >> 16) & 1u);            // RNE
  return (unsigned short)(u >> 16);
}

// packed f32x2 -> bf16x2 dword (v_cvt_pk_bf16_f32, RNE)
__device__ __forceinline__ unsigned int pkcv(float a, float b) {
  __hip_bfloat162 h = __float22bfloat162_rn(make_float2(a, b));
  unsigned int r; __builtin_memcpy(&r, &h, 4); return r;
}

__device__ __forceinline__ short8 ld8(const unsigned short* p) {
  return __builtin_bit_cast(short8, *(const ushort8_t*)p);
}

__device__ __forceinline__ short8 pack8f(float4_t a, float4_t b) {
  uint4_t u;
  u[0] = pkcv(a[0], a[1]); u[1] = pkcv(a[2], a[3]);
  u[2] = pkcv(b[0], b[1]); u[3] = pkcv(b[2], b[3]);
  return __builtin_bit_cast(short8, u);
}

__device__ __forceinline__ float16_t z16() {
  float16_t r;
#pragma unroll
  for (int i = 0; i < 16; ++i) r[i] = 0.0f;
  return r;
}

// async global->LDS DMA: 64 lanes x 16B; LDS dst = wave-uniform base
typedef __attribute__((address_space(1))) const void* gvp;
typedef __attribute__((address_space(3))) void*       lvp;
__device__ __forceinline__ void dma16(const unsigned short* g, unsigned short* l) {
  __builtin_amdgcn_global_load_lds((gvp)g, (lvp)l, 16, 0, 0);
}

#define MFMA(a, b, c) __builtin_amdgcn_mfma_f32_32x32x16_bf16((a), (b), (c), 0, 0, 0)

// ws layout (u16 units)
#define QOFF  0                // 4*128*4*512 = 1048576 each
#define KOFF  1048576
#define VOFF  2097152
#define WQOFF 3145728          // 192*256
#define BSOFF 3194880          // scaled qkv bias, fp32 (192)

// ---------------------------------------------------------------------------
// k_prep: grid 24 x 256. qkv_w -> bf16 frag layout (Q rows scaled by QSC);
// bias -> fp32 with Q-scale fold.
// ---------------------------------------------------------------------------
__global__ void k_prep(const float* __restrict__ qw, const float* __restrict__ qb,
                       unsigned short* __restrict__ wqs, float* __restrict__ bs)
{
  const int g = blockIdx.x * 256 + threadIdx.x;   // 0..6143
  {
    const int lane = g & 63, grp = g >> 6;
    const int w6 = grp >> 4, kk = grp & 15;
    const int o = w6 * 32 + (lane & 31);
    const int c = kk * 16 + (lane >> 5) * 8;
    const float sc = (o < 64) ? QSC : 1.0f;
    const float* src = qw + o * 256 + c;
    ushort8_t u;
#pragma unroll
    for (int j = 0; j < 8; ++j) u[j] = f2bf(src[j] * sc);
    *(ushort8_t*)(wqs + g * 8) = u;
  }
  if (g < 48) {
    float4_t f = *(const float4_t*)(qb + g * 4);
    float4_t o;
#pragma unroll
    for (int j = 0; j < 4; ++j) o[j] = f[j] * ((g * 4 + j) < 64 ? QSC : 1.0f);
    *(float4_t*)(bs + g * 4) = o;
  }
}

// ---------------------------------------------------------------------------
// k_qkv: grid 256 x 384 thr (6 waves). Block: 64-token tile, all 192 o.
// Xl XOR-granule swizzle: dword (n, cp) lives at
//   n*128 + (((cp>>2) ^ ((n>>2)&7))<<2) + (cp&3)
// Writes: 2-way conflict (free). b128 reads: perfect 32-bank coverage.
// ---------------------------------------------------------------------------
__device__ __forceinline__ int xsw(int n, int cp) {
  return n * 128 + ((((cp >> 2) ^ ((n >> 2) & 7)) << 2) | (cp & 3));
}

__global__ __launch_bounds__(384, 2) void k_qkv(
    const float* __restrict__ x, const unsigned short* __restrict__ wqs,
    const float* __restrict__ bs, unsigned short* __restrict__ Qf,
    unsigned short* __restrict__ Kf, unsigned short* __restrict__ Vf)
{
  __shared__ unsigned int Xl[64 * 128];
  const int id = blockIdx.x;
  const int b  = id & 3;                        // XCD-affine batch
  const int nt = id >> 2;                       // 0..63 (64-token tile)
  const int t  = threadIdx.x;
  const int n0g = nt * 64;

  if (t < 256) {
    const int n0  = (t & 15) * 4;
    const int cpb = t >> 4;                      // 0..15
#pragma unroll
    for (int p = 0; p < 8; ++p) {
      const int cp = cpb + 16 * p, c = cp * 2;
      const float* xb = x + (((size_t)(b * DIM + c)) << 12) + n0g + n0;
      float4_t a = *(const float4_t*)xb;
      float4_t d = *(const float4_t*)(xb + 4096);
#pragma unroll
      for (int j = 0; j < 4; ++j)
        Xl[xsw(n0 + j, cp)] = pkcv(a[j], d[j]);
    }
  }
  __syncthreads();

  const int w = t >> 6, lane = t & 63, l31 = lane & 31, lh = lane >> 5;
  const unsigned short* wrow = wqs + ((w * 16) << 9) + lane * 8;
  const unsigned int*   xb0  = &Xl[l31 * 128];
  const int sw = (l31 >> 2) & 7;

  float16_t a0 = z16(), a1 = z16();
  if (w < 4) {
#pragma unroll
    for (int kk = 0; kk < 16; ++kk) {
      const int idx = ((lh + 2 * kk) ^ sw) << 2;
      short8 wf = ld8(wrow + (kk << 9));
      short8 x0 = __builtin_bit_cast(short8, *(const uint4_t*)(xb0 + idx));
      short8 x1 = __builtin_bit_cast(short8, *(const uint4_t*)(xb0 + 4096 + idx));
      a0 = MFMA(wf, x0, a0);                     // C[o rows][n cols], sub 0
      a1 = MFMA(wf, x1, a1);                     // sub 1
    }
  } else {
#pragma unroll
    for (int kk = 0; kk < 16; ++kk) {
      const int idx = ((lh + 2 * kk) ^ sw) << 2;
      short8 wf = ld8(wrow + (kk << 9));
      short8 x0 = __builtin_bit_cast(short8, *(const uint4_t*)(xb0 + idx));
      short8 x1 = __builtin_bit_cast(short8, *(const uint4_t*)(xb0 + 4096 + idx));
      a0 = MFMA(x0, wf, a0);                     // C[token rows][c cols]
      a1 = MFMA(x1, wf, a1);
    }
  }

  if (w < 4) {
    unsigned short* dst = (w < 2) ? Qf : Kf;
    const int w2 = w & 1;                        // c64-half of Q or K
#pragma unroll
    for (int sub = 0; sub < 2; ++sub) {
      const float16_t& aa = sub ? a1 : a0;
      const int ch = nt * 2 + sub;               // global 32-token chunk
#pragma unroll
      for (int p = 0; p < 4; ++p) {
        const int o = w * 32 + p * 8 + lh * 4;   // global qkv channel
        float4_t bv = *(const float4_t*)(bs + o);
        uint2_t u2;
        u2[0] = pkcv(aa[p * 4 + 0] + bv[0], aa[p * 4 + 1] + bv[1]);
        u2[1] = pkcv(aa[p * 4 + 2] + bv[2], aa[p * 4 + 3] + bv[3]);
        const int kkt = w2 * 2 + (p >> 1);
        *(uint2_t*)(dst + ((((b * 128 + ch) * 4 + kkt) << 9)
                           + (l31 + 32 * (p & 1)) * 8 + lh * 4)) = u2;
      }
    }
  } else {
    const int ct = w - 4;                        // c-group of V
    const float bvs = bs[128 + ct * 32 + l31];
#pragma unroll
    for (int sub = 0; sub < 2; ++sub) {
      const float16_t& aa = sub ? a1 : a0;
      const int ch = nt * 2 + sub;
#pragma unroll
      for (int ks = 0; ks < 2; ++ks) {
        uint4_t u4;
#pragma unroll
        for (int j = 0; j < 4; ++j)
          u4[j] = pkcv(aa[ks * 8 + 2 * j] + bvs, aa[ks * 8 + 2 * j + 1] + bvs);
        *(uint4_t*)(Vf + ((((b * 128 + ch) * 4 + ct * 2 + ks) << 9)
                          + lane * 8)) = u4;
      }
    }
  }
}

// ---------------------------------------------------------------------------
// k_attn: grid 256 x 512 thr (8 waves). Block: 64 q-rows.
// Outer: 16 tiles of 256 tokens (8 chunks), LDS dbuf via global_load_lds.
// Staging: waves 0-3 K chunks {2w,2w+1}; waves 4-7 V likewise (8KB/wave/tile).
// Compute: wave wv -> m-chunks {2mq, 2mq+1} of the tile, n-subtile (wv&1).
// den accumulated by MFMA against a ones-fragment (zero VALU cost).
// ---------------------------------------------------------------------------
#define OS   68    // Oacc row stride (fp32)
#define OLS  72    // Ol row stride (bf16)
#define NACC (64 * OS + 64)

__global__ __launch_bounds__(512, 1) void k_attn(
    const unsigned short* __restrict__ Qf, const unsigned short* __restrict__ Kf,
    const unsigned short* __restrict__ Vf, const float* __restrict__ pw,
    const float* __restrict__ pb, float* __restrict__ out)
{
  __shared__ __align__(16) unsigned short KV[2][2][16384]; // [buf][K|V][8ch*2048]
  __shared__ float Oacc[NACC];                             // O[n][c] + den tail
  __shared__ __align__(16) unsigned short Ol[64 * OLS];

  const int id = blockIdx.x;
  const int b  = id & 3;                             // XCD-affine batch
  const int nt = id >> 2;                            // 0..63
  const int t  = threadIdx.x;
  const int wv = t >> 6, lane = t & 63, l31 = lane & 31, lh = lane >> 5;
  const int mq = wv >> 1, nsub = wv & 1;

  for (int i = t; i < NACC; i += 512) Oacc[i] = 0.0f;

  // staging role: wave stages 2 chunks of K (wv<4) or V (wv>=4)
  const int kvsel = wv >> 2;
  const int wq2   = (wv & 3) * 2;                    // first staged chunk in tile
  const unsigned short* sg = ((kvsel == 0) ? Kf : Vf)
                             + (((size_t)(b * 128 + wq2)) << 11) + lane * 8;

  // Q frags (QSC pre-folded)
  short8 qf[4];
#pragma unroll
  for (int kk = 0; kk < 4; ++kk)
    qf[kk] = ld8(Qf + (((b * 128 + nt * 2 + nsub) * 4 + kk) << 9) + lane * 8);

  // ones B-frag for den-MFMA
  uint4_t one4; one4[0] = 0x3F803F80u; one4[1] = 0x3F803F80u;
  one4[2] = 0x3F803F80u; one4[3] = 0x3F803F80u;
  const short8 ONES = __builtin_bit_cast(short8, one4);

  // stage tile 0 into buf 0
#pragma unroll
  for (int c2 = 0; c2 < 2; ++c2)
#pragma unroll
    for (int kk = 0; kk < 4; ++kk)
      dma16(sg + (c2 << 11) + (kk << 9),
            &KV[0][kvsel][((wq2 + c2) << 11) + (kk << 9)]);

  float16_t oc0 = z16(), oc1 = z16(), dacc = z16();

  __syncthreads();   // Oacc zeroed + tile 0 resident

  for (int t4 = 0; t4 < 16; ++t4) {
    const int cur = t4 & 1;

    // stage tile t4+1 (drained at the NEXT barrier, a full tile later)
    if (t4 < 15) {
      const unsigned short* g = sg + (((size_t)(t4 + 1)) << 14);
#pragma unroll
      for (int c2 = 0; c2 < 2; ++c2)
#pragma unroll
        for (int kk = 0; kk < 4; ++kk)
          dma16(g + (c2 << 11) + (kk << 9),
                &KV[cur ^ 1][kvsel][((wq2 + c2) << 11) + (kk << 9)]);
    }

#pragma unroll
    for (int cc = 0; cc < 2; ++cc) {
      const int ch = mq * 2 + cc;                    // my m-chunk in tile
      const unsigned short* kl = &KV[cur][0][ch << 11];
      const unsigned short* vl = &KV[cur][1][ch << 11];

      short8 kf0 = ld8(kl + lane * 8);
      short8 kf1 = ld8(kl + 512 + lane * 8);
      short8 kf2 = ld8(kl + 1024 + lane * 8);
      short8 kf3 = ld8(kl + 1536 + lane * 8);

      // S^T tile: lane col n = l31, row m = (e&3)+8*(e>>2)+4*lh
      float16_t s = z16();
      s = MFMA(kf0, qf[0], s);
      s = MFMA(kf1, qf[1], s);
      s = MFMA(kf2, qf[2], s);
      s = MFMA(kf3, qf[3], s);

      float p[16];
#pragma unroll
      for (int e = 0; e < 16; ++e) p[e] = PEXP(s[e]);

      // S regs ARE the O-MFMA A-operand (V k-slots pre-permuted at production)
      uint4_t w0, w1;
#pragma unroll
      for (int j = 0; j < 4; ++j) {
        w0[j] = pkcv(p[2 * j], p[2 * j + 1]);
        w1[j] = pkcv(p[8 + 2 * j], p[9 + 2 * j]);
      }
      short8 pf0 = __builtin_bit_cast(short8, w0);   // m 0..15 of chunk
      short8 pf1 = __builtin_bit_cast(short8, w1);   // m 16..31

      short8 vf0 = ld8(vl + lane * 8);               // ct0 ks0
      short8 vf1 = ld8(vl + 512 + lane * 8);         // ct0 ks1
      short8 vf2 = ld8(vl + 1024 + lane * 8);        // ct1 ks0
      short8 vf3 = ld8(vl + 1536 + lane * 8);        // ct1 ks1

      oc0  = MFMA(pf0, vf0, oc0);
      oc0  = MFMA(pf1, vf1, oc0);
      oc1  = MFMA(pf0, vf2, oc1);
      oc1  = MFMA(pf1, vf3, oc1);
      dacc = MFMA(pf0, ONES, dacc);                  // den[n] in every col
      dacc = MFMA(pf1, ONES, dacc);
    }

    __syncthreads();   // drains next-tile DMA + frees cur buffer
  }

  // combine m-chunk partials: O[n][c] + den via LDS atomics
#pragma unroll
  for (int ct = 0; ct < 2; ++ct) {
    const float16_t& oa = ct ? oc1 : oc0;
    const int cc = ct * 32 + l31;
#pragma unroll
    for (int e = 0; e < 16; ++e) {
      const int nr = nsub * 32 + (e & 3) + 8 * (e >> 2) + 4 * lh;
      atomicAdd(&Oacc[nr * OS + cc], oa[e]);
    }
  }
  if (l31 == 0) {   // dacc cols identical; lh 0/1 cover the 32 rows
#pragma unroll
    for (int e = 0; e < 16; ++e) {
      const int nr = nsub * 32 + (e & 3) + 8 * (e >> 2) + 4 * lh;
      atomicAdd(&Oacc[64 * OS + nr], dacc[e]);
    }
  }
  __syncthreads();

  // normalize + cast -> Ol[n][c] bf16 (8 thr/row)
  {
    const int nloc = t >> 3, c8 = (t & 7) * 8;
    float4_t s0 = *(float4_t*)&Oacc[nloc * OS + c8];
    float4_t s1 = *(float4_t*)&Oacc[nloc * OS + c8 + 4];
    const float r = 1.0f / Oacc[64 * OS + nloc];
    uint4_t o4;
    o4[0] = pkcv(s0[0] * r, s0[1] * r);
    o4[1] = pkcv(s0[2] * r, s0[3] * r);
    o4[2] = pkcv(s1[0] * r, s1[1] * r);
    o4[3] = pkcv(s1[2] * r, s1[3] * r);
    *(uint4_t*)&Ol[nloc * OLS + c8] = o4;
  }
  __syncthreads();

  // fused proj: wave wv -> o-tile wv (32 o), both n-subtiles; raw fp32 W
  float16_t f0 = z16(), f1 = z16();
  const float* pwrow = pw + (wv * 32 + l31) * 64 + lh * 8;
#pragma unroll
  for (int kk = 0; kk < 4; ++kk) {
    float4_t wa = *(const float4_t*)(pwrow + kk * 16);
    float4_t wb = *(const float4_t*)(pwrow + kk * 16 + 4);
    short8 af = pack8f(wa, wb);
    short8 b0 = ld8(&Ol[l31 * OLS + kk * 16 + lh * 8]);
    short8 b1 = ld8(&Ol[(32 + l31) * OLS + kk * 16 + lh * 8]);
    f0 = MFMA(af, b0, f0);
    f1 = MFMA(af, b1, f1);
  }
  const int n0 = nt * 64;
#pragma unroll
  for (int e = 0; e < 16; ++e) {
    const int o = wv * 32 + (e & 3) + 8 * (e >> 2) + 4 * lh;
    const float bv = pb[o];
    out[((b * 256 + o) << 12) + n0 + l31]      = f0[e] + bv;
    out[((b * 256 + o) << 12) + n0 + 32 + l31] = f1[e] + bv;
  }
}

extern "C" void kernel_launch(void* const* d_in, const int* in_sizes, int n_in,
                              void* d_out, int out_size, void* d_ws, size_t ws_size,
                              hipStream_t stream) {
  const float* x      = (const float*)d_in[0];
  const float* qkv_w  = (const float*)d_in[1];
  const float* qkv_b  = (const float*)d_in[2];
  const float* proj_w = (const float*)d_in[3];
  const float* proj_b = (const float*)d_in[4];
  float* out = (float*)d_out;

  unsigned short* ws  = (unsigned short*)d_ws;
  unsigned short* qf  = ws + QOFF;
  unsigned short* kf  = ws + KOFF;
  unsigned short* vf  = ws + VOFF;
  unsigned short* wqs = ws + WQOFF;
  float*          bs  = (float*)(ws + BSOFF);

  k_prep<<<24, 256, 0, stream>>>(qkv_w, qkv_b, wqs, bs);
  k_qkv<<<256, 384, 0, stream>>>(x, wqs, bs, qf, kf, vf);
  k_attn<<<256, 512, 0, stream>>>(qf, kf, vf, proj_w, proj_b, out);
}